// Round 1
// baseline (103.155 us; speedup 1.0000x reference)
//
#include <hip/hip_runtime.h>

// DualCompressor: y_fwd[v,m] = log(sum_k exp(d_out_t[v,k] + alpha_fwd[m,k]))
//                 y_bwd[v,m] = log(sum_k exp(d_in_t[v,k]  + alpha_bwd[m,k]))
// SIGMA = 1.0 so the /sigma and *sigma are identity.
//
// Restructure: log(sum_k exp(phi_k)*exp(alpha_mk)) — precompute exp(alpha)
// (2x16x64 = 2048 floats, in LDS per block), exp(phi) once per row, then the
// m-loop is pure FMA dot products. Cuts exp count 16x; kernel is memory-bound
// (64 MB total traffic, ~10 us floor at 6.3 TB/s).
//
// Wave mapping: block = 256 = 4 waves; wave index 'sub' selects
// (compressor c, m-half h) so all ealpha LDS reads are wave-uniform
// (HW broadcast, zero bank conflicts). Lane = local row.

#define K_DIM 64
#define M_HALF 16

__global__ __launch_bounds__(256) void dual_compress_kernel(
    const float* __restrict__ d_out_t,
    const float* __restrict__ d_in_t,
    const float* __restrict__ alpha_fwd,
    const float* __restrict__ alpha_bwd,
    float* __restrict__ out, int V)
{
    // exp(alpha): rows 0..15 = fwd, rows 16..31 = bwd; row stride 64 floats.
    __shared__ float ealpha[32 * K_DIM];

    int tid = threadIdx.x;
    #pragma unroll
    for (int it = 0; it < 8; ++it) {
        int i = tid + it * 256;                       // 0..2047
        float a = (i < 1024) ? alpha_fwd[i] : alpha_bwd[i - 1024];
        ealpha[i] = __expf(a);
    }
    __syncthreads();

    int lane = tid & 63;
    int sub  = tid >> 6;        // wave id within block: 0..3
    int c    = sub >> 1;        // 0 = fwd (d_out_t), 1 = bwd (d_in_t)
    int h    = sub & 1;         // which half of the 16 m's
    int v    = blockIdx.x * 64 + lane;
    if (v >= V) return;

    const float* phi = (c == 0 ? d_out_t : d_in_t) + (size_t)v * K_DIM;

    // exp(phi row) into registers (16 x float4 = 64 VGPRs)
    float4 e4[16];
    #pragma unroll
    for (int i = 0; i < 16; ++i) {
        float4 p = ((const float4*)phi)[i];
        e4[i].x = __expf(p.x);
        e4[i].y = __expf(p.y);
        e4[i].z = __expf(p.z);
        e4[i].w = __expf(p.w);
    }

    // 8 dot products of length 64 against wave-uniform LDS rows
    const float4* arow_base = (const float4*)&ealpha[(c * 16 + h * 8) * K_DIM];

    float y[8];
    #pragma unroll
    for (int mi = 0; mi < 8; ++mi) {
        const float4* a4 = arow_base + mi * 16;
        float acc = 0.0f;
        #pragma unroll
        for (int k = 0; k < 16; ++k) {
            float4 a = a4[k];
            acc = fmaf(e4[k].x, a.x, acc);
            acc = fmaf(e4[k].y, a.y, acc);
            acc = fmaf(e4[k].z, a.z, acc);
            acc = fmaf(e4[k].w, a.w, acc);
        }
        y[mi] = __logf(acc);
    }

    // output: y_fwd (V x 16) then y_bwd (V x 16), this thread owns 8 of row v
    float* orow = out + ((size_t)c * V + v) * 16 + (size_t)h * 8;
    ((float4*)orow)[0] = make_float4(y[0], y[1], y[2], y[3]);
    ((float4*)orow)[1] = make_float4(y[4], y[5], y[6], y[7]);
}

extern "C" void kernel_launch(void* const* d_in, const int* in_sizes, int n_in,
                              void* d_out, int out_size, void* d_ws, size_t ws_size,
                              hipStream_t stream) {
    const float* d_out_t   = (const float*)d_in[0];
    const float* d_in_t    = (const float*)d_in[1];
    const float* alpha_fwd = (const float*)d_in[2];
    const float* alpha_bwd = (const float*)d_in[3];
    float* out = (float*)d_out;

    int V = in_sizes[0] / K_DIM;          // 100000
    int grid = (V + 63) / 64;             // 64 rows per block

    dual_compress_kernel<<<grid, 256, 0, stream>>>(
        d_out_t, d_in_t, alpha_fwd, alpha_bwd, out, V);
}

// Round 2
// 100.885 us; speedup vs baseline: 1.0225x; 1.0225x over previous
//
#include <hip/hip_runtime.h>

// DualCompressor: y_fwd[v,m] = log(sum_k exp(d_out_t[v,k] + alpha_fwd[m,k]))
//                 y_bwd[v,m] = log(sum_k exp(d_in_t[v,k]  + alpha_bwd[m,k]))
// SIGMA = 1.0.
//
// log(sum_k exp(phi_k)*exp(alpha_mk)): precompute exp(alpha) in LDS (2 KB/c),
// exp(phi) once per row, then 16 pure-FMA dot products per row.
//
// R1 change: one wave handles ALL 16 m's for its compressor, so each phi row
// is fetched+exp'd exactly once (R0 fetched each row twice -> 102 MB HBM,
// 18.3 us; ideal is 51.2+12.8 = 64 MB -> 10.2 us at 6.3 TB/s).
//
// Mapping: block 256 = 4 waves over 128 rows; wave w: c = w&1 (0=fwd,1=bwd),
// row-half = w>>1. All ealpha LDS reads are wave-uniform -> HW broadcast,
// zero bank conflicts.

#define K_DIM 64

__global__ __launch_bounds__(256) void dual_compress_kernel(
    const float* __restrict__ d_out_t,
    const float* __restrict__ d_in_t,
    const float* __restrict__ alpha_fwd,
    const float* __restrict__ alpha_bwd,
    float* __restrict__ out, int V)
{
    // exp(alpha): [c][m][k], c=0 fwd rows 0..15, c=1 bwd rows 16..31
    __shared__ float ealpha[32 * K_DIM];

    int tid = threadIdx.x;
    #pragma unroll
    for (int it = 0; it < 8; ++it) {
        int i = tid + it * 256;                       // 0..2047
        float a = (i < 1024) ? alpha_fwd[i] : alpha_bwd[i - 1024];
        ealpha[i] = __expf(a);
    }
    __syncthreads();

    int lane = tid & 63;
    int w    = tid >> 6;        // wave id: 0..3
    int c    = w & 1;           // 0 = fwd (d_out_t), 1 = bwd (d_in_t)
    int rh   = w >> 1;          // row half within the block's 128 rows
    int v    = blockIdx.x * 128 + rh * 64 + lane;
    if (v >= V) return;

    const float* phi = (c == 0 ? d_out_t : d_in_t) + (size_t)v * K_DIM;

    // exp(phi row) into registers (16 x float4 = 64 VGPRs)
    float4 e4[16];
    #pragma unroll
    for (int i = 0; i < 16; ++i) {
        float4 p = ((const float4*)phi)[i];
        e4[i].x = __expf(p.x);
        e4[i].y = __expf(p.y);
        e4[i].z = __expf(p.z);
        e4[i].w = __expf(p.w);
    }

    // 16 dot products of length 64 against wave-uniform LDS rows
    const float4* arow_base = (const float4*)&ealpha[c * 16 * K_DIM];

    float y[16];
    #pragma unroll
    for (int mi = 0; mi < 16; ++mi) {
        const float4* a4 = arow_base + mi * 16;
        float acc = 0.0f;
        #pragma unroll
        for (int k = 0; k < 16; ++k) {
            float4 a = a4[k];
            acc = fmaf(e4[k].x, a.x, acc);
            acc = fmaf(e4[k].y, a.y, acc);
            acc = fmaf(e4[k].z, a.z, acc);
            acc = fmaf(e4[k].w, a.w, acc);
        }
        y[mi] = __logf(acc);
    }

    // output: y_fwd (V x 16) then y_bwd (V x 16); this thread owns row v of c
    float* orow = out + ((size_t)c * V + v) * 16;
    #pragma unroll
    for (int i = 0; i < 4; ++i)
        ((float4*)orow)[i] = make_float4(y[4*i], y[4*i+1], y[4*i+2], y[4*i+3]);
}

extern "C" void kernel_launch(void* const* d_in, const int* in_sizes, int n_in,
                              void* d_out, int out_size, void* d_ws, size_t ws_size,
                              hipStream_t stream) {
    const float* d_out_t   = (const float*)d_in[0];
    const float* d_in_t    = (const float*)d_in[1];
    const float* alpha_fwd = (const float*)d_in[2];
    const float* alpha_bwd = (const float*)d_in[3];
    float* out = (float*)d_out;

    int V = in_sizes[0] / K_DIM;          // 100000
    int grid = (V + 127) / 128;           // 128 rows per block

    dual_compress_kernel<<<grid, 256, 0, stream>>>(
        d_out_t, d_in_t, alpha_fwd, alpha_bwd, out, V);
}